// Round 1
// 344.837 us; speedup vs baseline: 1.1484x; 1.1484x over previous
//
#include <hip/hip_runtime.h>
#include <math.h>

#define BN_EPS 1e-5f
#define SLOT 96              // padded CSR slots per node (avg deg ~17, P(>96)~0)
#define LN16 2.7725887f      // exp bias so packed-fp16 accumulators can't overflow
#define BCAP 5120            // per-bucket capacity (mean 4352, +11 sigma)

typedef _Float16 h2 __attribute__((ext_vector_type(2)));
typedef _Float16 h4 __attribute__((ext_vector_type(4)));
typedef _Float16 h8 __attribute__((ext_vector_type(8)));
typedef float f2v __attribute__((ext_vector_type(2)));
typedef float float4v __attribute__((ext_vector_type(4)));

static __device__ inline h2 bit_h2(unsigned u) {
    union { unsigned u; h2 h; } c; c.u = u; return c.h;
}
static __device__ inline unsigned bit_u(h2 h) {
    union { unsigned u; h2 h; } c; c.h = h; return c.u;
}

// DPP partial-sum adds (VALU pipe). 0xB1=quad xor1, 0x4E=quad xor2,
// 0x141=row_half_mirror (8-lane), 0x140=row_mirror (16-lane).
template <int CTRL>
static __device__ inline float dpp_add(float x) {
    int y = __builtin_amdgcn_update_dpp(0, __float_as_int(x), CTRL, 0xF, 0xF, true);
    return x + __int_as_float(y);
}
static __device__ inline float red8_dpp(float t) {
    t = dpp_add<0xB1>(t); t = dpp_add<0x4E>(t); t = dpp_add<0x141>(t);
    return t;
}
static __device__ inline float red16_dpp(float t) {
    t = dpp_add<0xB1>(t); t = dpp_add<0x4E>(t); t = dpp_add<0x141>(t);
    t = dpp_add<0x140>(t);
    return t;
}

// ---------------------------------------------------------------------------
// Weight packing: [p0|p1|p2] -> MFMA B-fragment-major fp16.
// ---------------------------------------------------------------------------
static __device__ inline void pack_one(int idx,
                                       const float* p0, const float* p1,
                                       const float* p2,
                                       int w0, int w1, int w2,
                                       int Ksrc, int Ncat,
                                       _Float16* out) {
    int k = idx / Ncat, n = idx - k * Ncat;
    float v = 0.f;
    if (k < Ksrc) {
        if (n < w0) v = p0[(size_t)k * w0 + n];
        else if (n < w0 + w1) v = p1[(size_t)k * w1 + (n - w0)];
        else if (w2 > 0 && n < w0 + w1 + w2) v = p2[(size_t)k * w2 + (n - w0 - w1)];
    }
    int kt = k >> 5, kr = k & 31;
    int quad = kr >> 3, j = kr & 7;
    int nt = n >> 4, nr = n & 15;
    int ntiles = Ncat >> 4;
    out[((size_t)(kt * ntiles + nt) * 64 + quad * 16 + nr) * 8 + j] = (_Float16)v;
}

// ---------------------------------------------------------------------------
// prep + bin (phase A), grid-stuffed.
// Bin: two-sweep per block. Sweep 1: LDS histogram over buckets (dst>>8).
// Reserve: one global atomicAdd per (block,bucket) -- ~100K low-contention
// atomics replace 850K random ones. Sweep 2: LDS-atomic rank, write packed
// (dlow<<16|src) into contiguous per-bucket runs (L2-coalescible).
// Prep: x fp32 -> A fp16 [N,128] zero-padded, 4 cols/thread (float4 in,
// 8B fp16 out); pack 3 weight tensors.
// ---------------------------------------------------------------------------
__global__ __launch_bounds__(256) void prep_bin_k(
    const int* __restrict__ src, const int* __restrict__ dst, int E, int Etot,
    int* __restrict__ gcnt, int* __restrict__ bbuf, int nbA,
    const float* __restrict__ x, _Float16* __restrict__ A, int N,
    const float* __restrict__ w1s, const float* __restrict__ w1d,
    const float* __restrict__ r0w, const float* __restrict__ w2s,
    const float* __restrict__ w2d, const float* __restrict__ w3s,
    const float* __restrict__ w3d, const float* __restrict__ r2w,
    _Float16* __restrict__ Wb1, _Float16* __restrict__ Wb2,
    _Float16* __restrict__ Wb3) {
    if ((int)blockIdx.x < nbA) {
        __shared__ int hist[256];
        __shared__ int base[256];
        int tid = threadIdx.x;
        hist[tid] = 0;
        __syncthreads();
        int per = (Etot + nbA - 1) / nbA;
        int e0 = blockIdx.x * per;
        int e1 = min(e0 + per, Etot);
        for (int i = e0 + tid; i < e1; i += 256) {
            int d = (i < E) ? dst[i] : (i - E);
            atomicAdd(&hist[d >> 8], 1);
        }
        __syncthreads();
        int h = hist[tid];
        if (h) base[tid] = atomicAdd(&gcnt[tid], h);
        __syncthreads();
        for (int i = e0 + tid; i < e1; i += 256) {
            int d = (i < E) ? dst[i] : (i - E);
            int s = (i < E) ? src[i] : (i - E);
            int b = d >> 8;
            int off = atomicAdd(&base[b], 1);
            if (off < BCAP) bbuf[(size_t)b * BCAP + off] = ((d & 255) << 16) | s;
        }
        return;
    }
    const int S1 = 128 * 384, S2 = 128 * 256, S3 = 128 * 144;
    int convTot = N * 32;
    int idx = (blockIdx.x - nbA) * 256 + threadIdx.x;
    if (idx < convTot) {
        int n = idx >> 5, t = idx & 31;
        float4 v = {0.f, 0.f, 0.f, 0.f};
        if (t < 25) v = *(const float4*)(x + (size_t)n * 100 + t * 4);
        h4 o = {(_Float16)v.x, (_Float16)v.y, (_Float16)v.z, (_Float16)v.w};
        *(h4*)(A + (size_t)n * 128 + t * 4) = o;
        return;
    }
    int p = idx - convTot;
    if (p < S1) pack_one(p, w1s, w1d, r0w, 128, 128, 128, 100, 384, Wb1);
    else if (p < S1 + S2) pack_one(p - S1, w2s, w2d, nullptr, 128, 128, 0, 128, 256, Wb2);
    else if (p < S1 + S2 + S3) pack_one(p - S1 - S2, w3s, w3d, r2w, 47, 47, 47, 128, 144, Wb3);
}

// ---------------------------------------------------------------------------
// MFMA fp16 GEMM, A-resident: one wave = one 16-row tile x ALL columns.
// Layer-1 launch additionally carries the bin phase B (scatN buckets, one
// block per bucket, dispatched FIRST so their latency hides under MFMA):
// build padded-CSR via LDS atomics (zero global atomics) + cached stores into
// a 98KB per-block window (XCD-L2 resident -> writebacks = dirty sectors
// only); also emits cnt[] (kills the old memset).
// ---------------------------------------------------------------------------
template <int NT>
__global__ __launch_bounds__(256) void mfma_gemm(const _Float16* __restrict__ A,
                                                 const _Float16* __restrict__ Bp,
                                                 _Float16* __restrict__ XLR,
                                                 float* __restrict__ RES,
                                                 int M, int Ncat,
                                                 int ncat_valid, int res_off,
                                                 int bf_remap, int bf_shift,
                                                 int bf_stride, int res_stride,
                                                 const int* __restrict__ gcnt,
                                                 const int* __restrict__ bbuf,
                                                 int* __restrict__ esrc,
                                                 int* __restrict__ cnt,
                                                 int scatN, int Nn) {
    __shared__ int lcnt[256];
    int bid = blockIdx.x;
    if (bid < scatN) {
        int tid = threadIdx.x;
        lcnt[tid] = 0;
        __syncthreads();
        int cb = gcnt[bid];
        if (cb > BCAP) cb = BCAP;
        const int* bp = bbuf + (size_t)bid * BCAP;
        int b0 = bid << 8;
        for (int i = tid; i < cb; i += 256) {
            int w = bp[i];
            int dl = (w >> 16) & 255;
            int s = w & 0xFFFF;
            int pos = atomicAdd(&lcnt[dl], 1);
            esrc[(size_t)(b0 + dl) * SLOT + pos] = s << 9;
        }
        __syncthreads();
        int d = b0 + tid;
        if (d < Nn) cnt[d] = lcnt[tid];
        return;
    }
    int mt = ((bid - scatN) * 256 + threadIdx.x) >> 6;
    int lane = threadIdx.x & 63;
    int mtiles = M >> 4;
    if (mt >= mtiles) return;
    int ngroups = Ncat / (16 * NT);
    int ntiles = Ncat >> 4;
    int quad = lane >> 4;
    int nr = lane & 15;
    int row = mt * 16 + nr;

    // whole-K A strip in registers (loaded once)
    h8 a[4];
#pragma unroll
    for (int kt = 0; kt < 4; kt++)
        a[kt] = *(const h8*)(A + (size_t)row * 128 + kt * 32 + quad * 8);

    int rowb = mt * 16 + quad * 4;
    for (int ng = 0; ng < ngroups; ng++) {
        float4v acc[NT];
#pragma unroll
        for (int t = 0; t < NT; t++) acc[t] = (float4v){0.f, 0.f, 0.f, 0.f};
#pragma unroll
        for (int kt = 0; kt < 4; kt++) {
            const _Float16* bbase =
                Bp + ((size_t)(kt * ntiles + ng * NT) * 64 + lane) * 8;
#pragma unroll
            for (int t = 0; t < NT; t++) {
                h8 b = *(const h8*)(bbase + (size_t)t * 512);
                acc[t] = __builtin_amdgcn_mfma_f32_16x16x32_f16(a[kt], b, acc[t], 0, 0, 0);
            }
        }
#pragma unroll
        for (int t = 0; t < NT; t++) {
            int col = (ng * NT + t) * 16 + nr;
            if (col >= ncat_valid) continue;
            if (col < res_off) {
                int bc = (col >= bf_remap) ? col + bf_shift : col;
#pragma unroll
                for (int r = 0; r < 4; r++)
                    XLR[(size_t)(rowb + r) * bf_stride + bc] = (_Float16)acc[t][r];
            } else {
                int rc = col - res_off;
#pragma unroll
                for (int r = 0; r < 4; r++)
                    RES[(size_t)(rowb + r) * res_stride + rc] = acc[t][r];
            }
        }
    }
}

// ---------------------------------------------------------------------------
// Fused GATv2 agg + epilogue, H=4 C=32. One wave per dst node; half-wave edge
// pairs; lane owns 4 channels as 2 packed fp16 pairs; 4 gathers in flight
// (8 edges per unrolled iteration); DPP 8-lane reduce; exp biased by -ln16.
// esrc = byte offsets. XLR rows 512 B: xl @0, xr @256.
// mode 1: h = relu(BN(agg + bias + RES + resB))     -> hbf fp16
// mode 2: h = relu(BN(agg + bias + fp16(hbf_prev))) -> hbf in-place
// ---------------------------------------------------------------------------
__global__ __launch_bounds__(256) void gat_agg4_fused(
    const int* __restrict__ cnt, const int* __restrict__ esrc,
    const _Float16* __restrict__ xlr, const float* __restrict__ att,
    const float* __restrict__ RES, const float* __restrict__ resB,
    const float* __restrict__ bias,
    const float* __restrict__ g, const float* __restrict__ bb,
    const float* __restrict__ mm, const float* __restrict__ vv,
    _Float16* __restrict__ hbf, int N, int mode) {
    int d = blockIdx.x * 4 + (threadIdx.x >> 6);
    if (d >= N) return;
    int lane = threadIdx.x & 63;
    int half = lane >> 5;
    int gl = lane & 31;
    int c0 = gl * 4;
    const char* xb = (const char*)xlr + c0 * 2;
    const h2 NS = {(_Float16)0.2f, (_Float16)0.2f};

    uint2 xrv = *(const uint2*)(xb + (size_t)d * 512 + 256);
    h2 xr01 = bit_h2(xrv.x), xr23 = bit_h2(xrv.y);
    float4 af = *(const float4*)(att + c0);
    h2 at01 = {(_Float16)af.x, (_Float16)af.y};
    h2 at23 = {(_Float16)af.z, (_Float16)af.w};

    int beg = d * SLOT;
    int end = beg + cnt[d];
    float den = 0.f;
    h2 acc01 = {(_Float16)0.f, (_Float16)0.f};
    h2 acc23 = acc01;
    int j = beg;
    // 8 edges per iteration: 4 gathers in flight per lane
    for (; j + 8 <= end; j += 8) {
        uint2 u[4];
#pragma unroll
        for (int q = 0; q < 4; q++) {
            int o = esrc[j + 2 * q + half];
            u[q] = *(const uint2*)(xb + o);
        }
#pragma unroll
        for (int q = 0; q < 4; q++) {
            h2 a01 = bit_h2(u[q].x), a23 = bit_h2(u[q].y);
            h2 v01 = a01 + xr01, v23 = a23 + xr23;
            v01 = __builtin_elementwise_max(v01, v01 * NS);
            v23 = __builtin_elementwise_max(v23, v23 * NS);
            h2 t2 = v01 * at01 + v23 * at23;
            f2v tf = __builtin_convertvector(t2, f2v);
            float t = red8_dpp(tf.x + tf.y);
            float p = __expf(t - LN16);
            den += p;
            h2 P = {(_Float16)p, (_Float16)p};
            acc01 = P * a01 + acc01;
            acc23 = P * a23 + acc23;
        }
    }
    for (; j < end; j += 2) {
        int jj = j + half;
        bool act = jj < end;
        int o = esrc[act ? jj : (end - 1)];
        uint2 u0 = *(const uint2*)(xb + o);
        h2 a01 = bit_h2(u0.x), a23 = bit_h2(u0.y);
        h2 v01 = a01 + xr01, v23 = a23 + xr23;
        v01 = __builtin_elementwise_max(v01, v01 * NS);
        v23 = __builtin_elementwise_max(v23, v23 * NS);
        h2 t2 = v01 * at01 + v23 * at23;
        f2v tf = __builtin_convertvector(t2, f2v);
        float t = red8_dpp(tf.x + tf.y);
        float p = act ? __expf(t - LN16) : 0.f;
        den += p;
        h2 P = {(_Float16)p, (_Float16)p};
        acc01 = P * a01 + acc01;
        acc23 = P * a23 + acc23;
    }
    den += __shfl_xor(den, 32);
    f2v c01 = __builtin_convertvector(acc01, f2v);
    f2v c23 = __builtin_convertvector(acc23, f2v);
    float f0 = c01.x, f1 = c01.y, fA = c23.x, fB = c23.y;
    f0 += __shfl_xor(f0, 32);
    f1 += __shfl_xor(f1, 32);
    fA += __shfl_xor(fA, 32);
    fB += __shfl_xor(fB, 32);

    if (half == 0) {
        float inv = 1.f / den;
        float4 bi = *(const float4*)(bias + c0);
        float o0 = f0 * inv + bi.x;
        float o1 = f1 * inv + bi.y;
        float o2 = fA * inv + bi.z;
        float o3 = fB * inv + bi.w;
        if (mode == 1) {
            float4 r = *(const float4*)(RES + (size_t)d * 128 + c0);
            float4 rb = *(const float4*)(resB + c0);
            o0 += r.x + rb.x; o1 += r.y + rb.y;
            o2 += r.z + rb.z; o3 += r.w + rb.w;
        } else {
            uint2 hv = *(const uint2*)(hbf + (size_t)d * 128 + c0);
            f2v g01 = __builtin_convertvector(bit_h2(hv.x), f2v);
            f2v g23 = __builtin_convertvector(bit_h2(hv.y), f2v);
            o0 += g01.x; o1 += g01.y; o2 += g23.x; o3 += g23.y;
        }
        float4 gm = *(const float4*)(mm + c0);
        float4 gv = *(const float4*)(vv + c0);
        float4 gg = *(const float4*)(g + c0);
        float4 gb = *(const float4*)(bb + c0);
        o0 = fmaxf((o0 - gm.x) * rsqrtf(gv.x + BN_EPS) * gg.x + gb.x, 0.f);
        o1 = fmaxf((o1 - gm.y) * rsqrtf(gv.y + BN_EPS) * gg.y + gb.y, 0.f);
        o2 = fmaxf((o2 - gm.z) * rsqrtf(gv.z + BN_EPS) * gg.z + gb.z, 0.f);
        o3 = fmaxf((o3 - gm.w) * rsqrtf(gv.w + BN_EPS) * gg.w + gb.w, 0.f);
        h2 s01 = {(_Float16)o0, (_Float16)o1};
        h2 s23 = {(_Float16)o2, (_Float16)o3};
        uint2 w;
        w.x = bit_u(s01);
        w.y = bit_u(s23);
        *(uint2*)(hbf + (size_t)d * 128 + c0) = w;
    }
}

// ---------------------------------------------------------------------------
// Fused GATv2 agg + epilogue, H=1 C=47 (layer 3). 16-lane edge groups,
// unroll-2, packed fp16 math, DPP 16-lane reduce. esrc byte offsets (>>1 for
// 256 B rows). XLR rows of 128 fp16: xl @0..47(pad), xr @64..111(pad).
// out = BN(agg + b3 + RES + res2_b), no relu.
// ---------------------------------------------------------------------------
__global__ __launch_bounds__(256) void gat_agg1_fused(
    const int* __restrict__ cnt, const int* __restrict__ esrc,
    const _Float16* __restrict__ xlr, const float* __restrict__ att,
    const float* __restrict__ RES, const float* __restrict__ resB,
    const float* __restrict__ bias,
    const float* __restrict__ g, const float* __restrict__ bb,
    const float* __restrict__ mm, const float* __restrict__ vv,
    float* __restrict__ out, int N) {
    int d = blockIdx.x * 4 + (threadIdx.x >> 6);
    if (d >= N) return;
    int lane = threadIdx.x & 63;
    int gl = lane & 15, grp = lane >> 4;
    const char* xb = (const char*)xlr + gl * 8;
    const h2 NS = {(_Float16)0.2f, (_Float16)0.2f};

    uint2 xrv = *(const uint2*)(xb + (size_t)d * 256 + 128);
    h2 xr01 = bit_h2(xrv.x), xr23 = bit_h2(xrv.y);
    float atf[4];
#pragma unroll
    for (int k = 0; k < 4; k++) {
        int c = gl * 4 + k;
        atf[k] = (c < 47) ? att[c] : 0.f;
    }
    h2 at01 = {(_Float16)atf[0], (_Float16)atf[1]};
    h2 at23 = {(_Float16)atf[2], (_Float16)atf[3]};

    int beg = d * SLOT;
    int end = beg + cnt[d];
    float den = 0.f;
    h2 acc01 = {(_Float16)0.f, (_Float16)0.f};
    h2 acc23 = acc01;
    int j = beg + grp;
    for (; j + 4 < end; j += 8) {
        int o0 = esrc[j] >> 1;
        int o1 = esrc[j + 4] >> 1;
        uint2 u0 = *(const uint2*)(xb + o0);
        uint2 u1 = *(const uint2*)(xb + o1);
        h2 a01 = bit_h2(u0.x), a23 = bit_h2(u0.y);
        h2 b01 = bit_h2(u1.x), b23 = bit_h2(u1.y);
        h2 v01 = a01 + xr01, v23 = a23 + xr23;
        h2 w01 = b01 + xr01, w23 = b23 + xr23;
        v01 = __builtin_elementwise_max(v01, v01 * NS);
        v23 = __builtin_elementwise_max(v23, v23 * NS);
        w01 = __builtin_elementwise_max(w01, w01 * NS);
        w23 = __builtin_elementwise_max(w23, w23 * NS);
        h2 t2a = v01 * at01 + v23 * at23;
        h2 t2b = w01 * at01 + w23 * at23;
        f2v ta = __builtin_convertvector(t2a, f2v);
        f2v tb = __builtin_convertvector(t2b, f2v);
        float t0 = red16_dpp(ta.x + ta.y);
        float t1 = red16_dpp(tb.x + tb.y);
        float p0 = __expf(t0 - LN16);
        float p1 = __expf(t1 - LN16);
        den += p0 + p1;
        h2 P0 = {(_Float16)p0, (_Float16)p0};
        h2 P1 = {(_Float16)p1, (_Float16)p1};
        acc01 = P0 * a01 + acc01;
        acc23 = P0 * a23 + acc23;
        acc01 = P1 * b01 + acc01;
        acc23 = P1 * b23 + acc23;
    }
    if (j < end) {
        int o = esrc[j] >> 1;
        uint2 u0 = *(const uint2*)(xb + o);
        h2 a01 = bit_h2(u0.x), a23 = bit_h2(u0.y);
        h2 v01 = a01 + xr01, v23 = a23 + xr23;
        v01 = __builtin_elementwise_max(v01, v01 * NS);
        v23 = __builtin_elementwise_max(v23, v23 * NS);
        h2 t2 = v01 * at01 + v23 * at23;
        f2v tf = __builtin_convertvector(t2, f2v);
        float t = red16_dpp(tf.x + tf.y);
        float p = __expf(t - LN16);
        den += p;
        h2 P = {(_Float16)p, (_Float16)p};
        acc01 = P * a01 + acc01;
        acc23 = P * a23 + acc23;
    }
    den += __shfl_xor(den, 16);
    den += __shfl_xor(den, 32);
    f2v c01 = __builtin_convertvector(acc01, f2v);
    f2v c23 = __builtin_convertvector(acc23, f2v);
    float f[4] = {c01.x, c01.y, c23.x, c23.y};
#pragma unroll
    for (int k = 0; k < 4; k++) {
        f[k] += __shfl_xor(f[k], 16);
        f[k] += __shfl_xor(f[k], 32);
    }
    if (grp == 0 && gl < 12) {
        float inv = 1.f / den;
#pragma unroll
        for (int k = 0; k < 4; k++) {
            int c = gl * 4 + k;
            if (c < 47) {
                float o = f[k] * inv + bias[c] + RES[(size_t)d * 48 + c] + resB[c];
                o = (o - mm[c]) * rsqrtf(vv[c] + BN_EPS) * g[c] + bb[c];
                out[(size_t)d * 47 + c] = o;
            }
        }
    }
}

// ---------------------------------------------------------------------------
extern "C" void kernel_launch(void* const* d_in, const int* in_sizes, int n_in,
                              void* d_out, int out_size, void* d_ws, size_t ws_size,
                              hipStream_t stream) {
    const float* x      = (const float*)d_in[0];
    const int*   ei     = (const int*)d_in[1];
    const float* w1_src = (const float*)d_in[2];
    const float* w1_dst = (const float*)d_in[3];
    const float* att1   = (const float*)d_in[4];
    const float* b1     = (const float*)d_in[5];
    const float* bn1_g  = (const float*)d_in[6];
    const float* bn1_b  = (const float*)d_in[7];
    const float* bn1_m  = (const float*)d_in[8];
    const float* bn1_v  = (const float*)d_in[9];
    const float* res0_w = (const float*)d_in[10];
    const float* res0_b = (const float*)d_in[11];
    const float* w2_src = (const float*)d_in[12];
    const float* w2_dst = (const float*)d_in[13];
    const float* att2   = (const float*)d_in[14];
    const float* b2     = (const float*)d_in[15];
    const float* bn2_g  = (const float*)d_in[16];
    const float* bn2_b  = (const float*)d_in[17];
    const float* bn2_m  = (const float*)d_in[18];
    const float* bn2_v  = (const float*)d_in[19];
    const float* w3_src = (const float*)d_in[20];
    const float* w3_dst = (const float*)d_in[21];
    const float* att3   = (const float*)d_in[22];
    const float* b3     = (const float*)d_in[23];
    const float* bn3_g  = (const float*)d_in[24];
    const float* bn3_b  = (const float*)d_in[25];
    const float* bn3_m  = (const float*)d_in[26];
    const float* bn3_v  = (const float*)d_in[27];
    const float* res2_w = (const float*)d_in[28];
    const float* res2_b = (const float*)d_in[29];

    const int F_IN = 100;
    const int KP = 128;
    const int NC1 = 384, NC2 = 256, NC3 = 144;
    int N = in_sizes[0] / F_IN;
    int E = in_sizes[1] / 2;
    int Etot = E + N;
    const int* src = ei;
    const int* dst = ei + E;
    int nbuck = (N + 255) >> 8;   // dst buckets of 256 nodes

    // ---- workspace layout (float units) ----
    float* ws = (float*)d_ws;
    size_t o = 0;
    _Float16* XLR = (_Float16*)(ws + o); o += (size_t)N * 128;   // [N,256] fp16
    float* B_res = ws + o; o += (size_t)N * 128;                 // residual fp32
    _Float16* A_h = (_Float16*)(ws + o); o += (size_t)N * 64;    // [N,128] fp16
    _Float16* Wb1 = (_Float16*)(ws + o); o += (size_t)KP * NC1 / 2;
    _Float16* Wb2 = (_Float16*)(ws + o); o += (size_t)KP * NC2 / 2;
    _Float16* Wb3 = (_Float16*)(ws + o); o += (size_t)KP * NC3 / 2;
    int* I_cnt  = (int*)(ws + o); o += N;
    int* I_esrc = (int*)(ws + o); o += (size_t)N * SLOT + 4;
    int* I_gcnt = (int*)(ws + o); o += 256;                      // bucket counts
    int* I_bbuf = (int*)(ws + o); o += (size_t)nbuck * BCAP;     // binned edges
    (void)ws_size; (void)n_in; (void)out_size;

    int mtiles = (N + 15) / 16;
    int aggGrid = (N + 3) / 4;
    int gemmGrid = (mtiles + 3) / 4;   // 1 wave per row-tile

    // 1. zero bucket counters (tiny)
    hipMemsetAsync(I_gcnt, 0, 256 * sizeof(int), stream);

    // 2. phase A binning + prep (vectorized conv + weight pack)
    {
        int nbA = 512;
        int convTot = N * 32;
        int packTot = KP * (NC1 + NC2 + NC3);
        int pb = (convTot + packTot + 255) / 256;
        prep_bin_k<<<nbA + pb, 256, 0, stream>>>(
            src, dst, E, Etot, I_gcnt, I_bbuf, nbA, x, A_h, N,
            w1_src, w1_dst, res0_w, w2_src, w2_dst, w3_src, w3_dst, res2_w,
            Wb1, Wb2, Wb3);
    }

    // 3. layer-1 GEMM (A-resident) + phase B CSR build (grid-stuffed first;
    //    its LDS-atomic latency hides under the MFMA work)
    mfma_gemm<4><<<nbuck + gemmGrid, 256, 0, stream>>>(
        A_h, Wb1, XLR, B_res, N, NC1, 384, 256, 384, 0, 256, 128,
        I_gcnt, I_bbuf, I_esrc, I_cnt, nbuck, N);
    // 4. layer-1 agg + epilogue
    gat_agg4_fused<<<aggGrid, 256, 0, stream>>>(
        I_cnt, I_esrc, XLR, att1, B_res, res0_b, b1,
        bn1_g, bn1_b, bn1_m, bn1_v, A_h, N, 1);

    // 5. layer-2 GEMM
    mfma_gemm<4><<<gemmGrid, 256, 0, stream>>>(
        A_h, Wb2, XLR, B_res, N, NC2, 256, 256, 256, 0, 256, 128,
        nullptr, nullptr, nullptr, nullptr, 0, N);
    // 6. layer-2 agg + epilogue
    gat_agg4_fused<<<aggGrid, 256, 0, stream>>>(
        I_cnt, I_esrc, XLR, att2, nullptr, nullptr, b2,
        bn2_g, bn2_b, bn2_m, bn2_v, A_h, N, 2);

    // 7. layer-3 GEMM
    mfma_gemm<3><<<gemmGrid, 256, 0, stream>>>(
        A_h, Wb3, XLR, B_res, N, NC3, 141, 94, 47, 17, 128, 48,
        nullptr, nullptr, nullptr, nullptr, 0, N);
    // 8. layer-3 agg + epilogue
    gat_agg1_fused<<<aggGrid, 256, 0, stream>>>(
        I_cnt, I_esrc, XLR, att3, B_res, res2_b, b3,
        bn3_g, bn3_b, bn3_m, bn3_v, (float*)d_out, N);
}

// Round 4
// 329.139 us; speedup vs baseline: 1.2031x; 1.0477x over previous
//
#include <hip/hip_runtime.h>
#include <math.h>

#define BN_EPS 1e-5f
#define SLOT 96              // padded CSR slots per node (avg deg ~17, P(>96)~0)
#define LN16 2.7725887f      // exp bias so packed-fp16 accumulators can't overflow
#define BCAP 5120            // per-bucket capacity (mean 4352, +11 sigma)

typedef _Float16 h2 __attribute__((ext_vector_type(2)));
typedef _Float16 h4 __attribute__((ext_vector_type(4)));
typedef _Float16 h8 __attribute__((ext_vector_type(8)));
typedef float f2v __attribute__((ext_vector_type(2)));
typedef float float4v __attribute__((ext_vector_type(4)));

static __device__ inline h2 bit_h2(unsigned u) {
    union { unsigned u; h2 h; } c; c.u = u; return c.h;
}
static __device__ inline unsigned bit_u(h2 h) {
    union { unsigned u; h2 h; } c; c.h = h; return c.u;
}

// DPP partial-sum adds (VALU pipe). 0xB1=quad xor1, 0x4E=quad xor2,
// 0x141=row_half_mirror (8-lane), 0x140=row_mirror (16-lane).
template <int CTRL>
static __device__ inline float dpp_add(float x) {
    int y = __builtin_amdgcn_update_dpp(0, __float_as_int(x), CTRL, 0xF, 0xF, true);
    return x + __int_as_float(y);
}
static __device__ inline float red8_dpp(float t) {
    t = dpp_add<0xB1>(t); t = dpp_add<0x4E>(t); t = dpp_add<0x141>(t);
    return t;
}
static __device__ inline float red16_dpp(float t) {
    t = dpp_add<0xB1>(t); t = dpp_add<0x4E>(t); t = dpp_add<0x141>(t);
    t = dpp_add<0x140>(t);
    return t;
}

// ---------------------------------------------------------------------------
// Weight packing: [p0|p1|p2] -> MFMA B-fragment-major fp16.
// ---------------------------------------------------------------------------
static __device__ inline void pack_one(int idx,
                                       const float* p0, const float* p1,
                                       const float* p2,
                                       int w0, int w1, int w2,
                                       int Ksrc, int Ncat,
                                       _Float16* out) {
    int k = idx / Ncat, n = idx - k * Ncat;
    float v = 0.f;
    if (k < Ksrc) {
        if (n < w0) v = p0[(size_t)k * w0 + n];
        else if (n < w0 + w1) v = p1[(size_t)k * w1 + (n - w0)];
        else if (w2 > 0 && n < w0 + w1 + w2) v = p2[(size_t)k * w2 + (n - w0 - w1)];
    }
    int kt = k >> 5, kr = k & 31;
    int quad = kr >> 3, j = kr & 7;
    int nt = n >> 4, nr = n & 15;
    int ntiles = Ncat >> 4;
    out[((size_t)(kt * ntiles + nt) * 64 + quad * 16 + nr) * 8 + j] = (_Float16)v;
}

// ---------------------------------------------------------------------------
// prep + bin (phase A), grid-stuffed.
// Bin: two-sweep per block. Sweep 1: LDS histogram over buckets (dst>>8).
// Reserve: one global atomicAdd per (block,bucket). Sweep 2: LDS-atomic
// rank, write packed (dlow<<16|src) into contiguous per-bucket runs.
// Prep: x fp32 -> A fp16 [N,128] zero-padded, vectorized; pack 3 weights.
// ---------------------------------------------------------------------------
__global__ __launch_bounds__(256) void prep_bin_k(
    const int* __restrict__ src, const int* __restrict__ dst, int E, int Etot,
    int* __restrict__ gcnt, int* __restrict__ bbuf, int nbA,
    const float* __restrict__ x, _Float16* __restrict__ A, int N,
    const float* __restrict__ w1s, const float* __restrict__ w1d,
    const float* __restrict__ r0w, const float* __restrict__ w2s,
    const float* __restrict__ w2d, const float* __restrict__ w3s,
    const float* __restrict__ w3d, const float* __restrict__ r2w,
    _Float16* __restrict__ Wb1, _Float16* __restrict__ Wb2,
    _Float16* __restrict__ Wb3) {
    if ((int)blockIdx.x < nbA) {
        __shared__ int hist[256];
        __shared__ int base[256];
        int tid = threadIdx.x;
        hist[tid] = 0;
        __syncthreads();
        int per = (Etot + nbA - 1) / nbA;
        int e0 = blockIdx.x * per;
        int e1 = min(e0 + per, Etot);
        for (int i = e0 + tid; i < e1; i += 256) {
            int d = (i < E) ? dst[i] : (i - E);
            atomicAdd(&hist[d >> 8], 1);
        }
        __syncthreads();
        int h = hist[tid];
        if (h) base[tid] = atomicAdd(&gcnt[tid], h);
        __syncthreads();
        for (int i = e0 + tid; i < e1; i += 256) {
            int d = (i < E) ? dst[i] : (i - E);
            int s = (i < E) ? src[i] : (i - E);
            int b = d >> 8;
            int off = atomicAdd(&base[b], 1);
            if (off < BCAP) bbuf[(size_t)b * BCAP + off] = ((d & 255) << 16) | s;
        }
        return;
    }
    const int S1 = 128 * 384, S2 = 128 * 256, S3 = 128 * 144;
    int convTot = N * 32;
    int idx = (blockIdx.x - nbA) * 256 + threadIdx.x;
    if (idx < convTot) {
        int n = idx >> 5, t = idx & 31;
        float4 v = {0.f, 0.f, 0.f, 0.f};
        if (t < 25) v = *(const float4*)(x + (size_t)n * 100 + t * 4);
        h4 o = {(_Float16)v.x, (_Float16)v.y, (_Float16)v.z, (_Float16)v.w};
        *(h4*)(A + (size_t)n * 128 + t * 4) = o;
        return;
    }
    int p = idx - convTot;
    if (p < S1) pack_one(p, w1s, w1d, r0w, 128, 128, 128, 100, 384, Wb1);
    else if (p < S1 + S2) pack_one(p - S1, w2s, w2d, nullptr, 128, 128, 0, 128, 256, Wb2);
    else if (p < S1 + S2 + S3) pack_one(p - S1 - S2, w3s, w3d, r2w, 47, 47, 47, 128, 144, Wb3);
}

// ---------------------------------------------------------------------------
// MFMA fp16 GEMM, A-resident: one wave = one 16-row tile x ALL columns.
// Layer-1 launch additionally carries the bin phase B (scatN buckets, one
// block per bucket, dispatched FIRST so their latency hides under MFMA):
// build padded-CSR via LDS atomics + cached stores into a 98KB per-block
// window; also emits cnt[].
// ---------------------------------------------------------------------------
template <int NT>
__global__ __launch_bounds__(256) void mfma_gemm(const _Float16* __restrict__ A,
                                                 const _Float16* __restrict__ Bp,
                                                 _Float16* __restrict__ XLR,
                                                 float* __restrict__ RES,
                                                 int M, int Ncat,
                                                 int ncat_valid, int res_off,
                                                 int bf_remap, int bf_shift,
                                                 int bf_stride, int res_stride,
                                                 const int* __restrict__ gcnt,
                                                 const int* __restrict__ bbuf,
                                                 int* __restrict__ esrc,
                                                 int* __restrict__ cnt,
                                                 int scatN, int Nn) {
    __shared__ int lcnt[256];
    int bid = blockIdx.x;
    if (bid < scatN) {
        int tid = threadIdx.x;
        lcnt[tid] = 0;
        __syncthreads();
        int cb = gcnt[bid];
        if (cb > BCAP) cb = BCAP;
        const int* bp = bbuf + (size_t)bid * BCAP;
        int b0 = bid << 8;
        for (int i = tid; i < cb; i += 256) {
            int w = bp[i];
            int dl = (w >> 16) & 255;
            int s = w & 0xFFFF;
            int pos = atomicAdd(&lcnt[dl], 1);
            esrc[(size_t)(b0 + dl) * SLOT + pos] = s << 9;
        }
        __syncthreads();
        int d = b0 + tid;
        if (d < Nn) cnt[d] = lcnt[tid];
        return;
    }
    int mt = ((bid - scatN) * 256 + threadIdx.x) >> 6;
    int lane = threadIdx.x & 63;
    int mtiles = M >> 4;
    if (mt >= mtiles) return;
    int ngroups = Ncat / (16 * NT);
    int ntiles = Ncat >> 4;
    int quad = lane >> 4;
    int nr = lane & 15;
    int row = mt * 16 + nr;

    // whole-K A strip in registers (loaded once)
    h8 a[4];
#pragma unroll
    for (int kt = 0; kt < 4; kt++)
        a[kt] = *(const h8*)(A + (size_t)row * 128 + kt * 32 + quad * 8);

    int rowb = mt * 16 + quad * 4;
    for (int ng = 0; ng < ngroups; ng++) {
        float4v acc[NT];
#pragma unroll
        for (int t = 0; t < NT; t++) acc[t] = (float4v){0.f, 0.f, 0.f, 0.f};
#pragma unroll
        for (int kt = 0; kt < 4; kt++) {
            const _Float16* bbase =
                Bp + ((size_t)(kt * ntiles + ng * NT) * 64 + lane) * 8;
#pragma unroll
            for (int t = 0; t < NT; t++) {
                h8 b = *(const h8*)(bbase + (size_t)t * 512);
                acc[t] = __builtin_amdgcn_mfma_f32_16x16x32_f16(a[kt], b, acc[t], 0, 0, 0);
            }
        }
#pragma unroll
        for (int t = 0; t < NT; t++) {
            int col = (ng * NT + t) * 16 + nr;
            if (col >= ncat_valid) continue;
            if (col < res_off) {
                int bc = (col >= bf_remap) ? col + bf_shift : col;
#pragma unroll
                for (int r = 0; r < 4; r++)
                    XLR[(size_t)(rowb + r) * bf_stride + bc] = (_Float16)acc[t][r];
            } else {
                int rc = col - res_off;
#pragma unroll
                for (int r = 0; r < 4; r++)
                    RES[(size_t)(rowb + r) * res_stride + rc] = acc[t][r];
            }
        }
    }
}

// ---------------------------------------------------------------------------
// Per-edge GATv2 micro-ops (packed fp16).
// ---------------------------------------------------------------------------
static __device__ inline void edge8(uint2 u, h2 xr01, h2 xr23, h2 at01,
                                    h2 at23, float& den, h2& acc01, h2& acc23,
                                    float gate) {
    const h2 NS = {(_Float16)0.2f, (_Float16)0.2f};
    h2 a01 = bit_h2(u.x), a23 = bit_h2(u.y);
    h2 v01 = a01 + xr01, v23 = a23 + xr23;
    v01 = __builtin_elementwise_max(v01, v01 * NS);
    v23 = __builtin_elementwise_max(v23, v23 * NS);
    h2 t2 = v01 * at01 + v23 * at23;
    f2v tf = __builtin_convertvector(t2, f2v);
    float t = red8_dpp(tf.x + tf.y);
    float p = __expf(t - LN16) * gate;
    den += p;
    h2 P = {(_Float16)p, (_Float16)p};
    acc01 = P * a01 + acc01;
    acc23 = P * a23 + acc23;
}
static __device__ inline void edge16(uint2 u, h2 xr01, h2 xr23, h2 at01,
                                     h2 at23, float& den, h2& acc01,
                                     h2& acc23, float gate) {
    const h2 NS = {(_Float16)0.2f, (_Float16)0.2f};
    h2 a01 = bit_h2(u.x), a23 = bit_h2(u.y);
    h2 v01 = a01 + xr01, v23 = a23 + xr23;
    v01 = __builtin_elementwise_max(v01, v01 * NS);
    v23 = __builtin_elementwise_max(v23, v23 * NS);
    h2 t2 = v01 * at01 + v23 * at23;
    f2v tf = __builtin_convertvector(t2, f2v);
    float t = red16_dpp(tf.x + tf.y);
    float p = __expf(t - LN16) * gate;
    den += p;
    h2 P = {(_Float16)p, (_Float16)p};
    acc01 = P * a01 + acc01;
    acc23 = P * a23 + acc23;
}

// ---------------------------------------------------------------------------
// Fused GATv2 agg + epilogue, H=4 C=32. One wave per dst node; half-wave edge
// pairs; lane owns 4 channels as 2 packed fp16 pairs; 4 gathers in flight.
// Edge offsets PRELOADED lane-parallel (1 coalesced load covers <=64 edges),
// then broadcast via __shfl. ALL control flow is wave-uniform (e, cnt_d
// uniform) so every __shfl executes with all 64 lanes active.
// esrc = byte offsets. XLR rows 512 B: xl @0, xr @256.
// mode 1: h = relu(BN(agg + bias + RES + resB))     -> hbf fp16
// mode 2: h = relu(BN(agg + bias + fp16(hbf_prev))) -> hbf in-place
// ---------------------------------------------------------------------------
__global__ __launch_bounds__(256) void gat_agg4_fused(
    const int* __restrict__ cnt, const int* __restrict__ esrc,
    const _Float16* __restrict__ xlr, const float* __restrict__ att,
    const float* __restrict__ RES, const float* __restrict__ resB,
    const float* __restrict__ bias,
    const float* __restrict__ g, const float* __restrict__ bb,
    const float* __restrict__ mm, const float* __restrict__ vv,
    _Float16* __restrict__ hbf, int N, int mode) {
    int d = blockIdx.x * 4 + (threadIdx.x >> 6);
    if (d >= N) return;
    int lane = threadIdx.x & 63;
    int half = lane >> 5;
    int gl = lane & 31;
    int c0 = gl * 4;
    const char* xb = (const char*)xlr + c0 * 2;

    int beg = d * SLOT;
    int cnt_d = cnt[d];
    int myoff = esrc[beg + lane];          // coalesced; junk beyond cnt_d unused

    uint2 xrv = *(const uint2*)(xb + (size_t)d * 512 + 256);
    h2 xr01 = bit_h2(xrv.x), xr23 = bit_h2(xrv.y);
    float4 af = *(const float4*)(att + c0);
    h2 at01 = {(_Float16)af.x, (_Float16)af.y};
    h2 at23 = {(_Float16)af.z, (_Float16)af.w};

    int nmain = cnt_d < 64 ? cnt_d : 64;
    float den = 0.f;
    h2 acc01 = {(_Float16)0.f, (_Float16)0.f};
    h2 acc23 = acc01;
    int e = 0;
    // 8 edges per iteration: 4 gathers in flight per lane, offsets via shfl
    for (; e + 8 <= nmain; e += 8) {
        uint2 u[4];
#pragma unroll
        for (int q = 0; q < 4; q++) {
            int o = __shfl(myoff, e + 2 * q + half);
            u[q] = *(const uint2*)(xb + o);
        }
#pragma unroll
        for (int q = 0; q < 4; q++)
            edge8(u[q], xr01, xr23, at01, at23, den, acc01, acc23, 1.f);
    }
    // remainder (2 at a time, predicated); also covers rare cnt>64 overflow
    for (; e < cnt_d; e += 2) {
        int ee = e + half;
        bool act = ee < cnt_d;
        int ec = act ? ee : cnt_d - 1;
        int o = __shfl(myoff, ec < 64 ? ec : 0);
        if (ec >= 64) o = esrc[beg + ec];
        uint2 u0 = *(const uint2*)(xb + o);
        edge8(u0, xr01, xr23, at01, at23, den, acc01, acc23, act ? 1.f : 0.f);
    }
    den += __shfl_xor(den, 32);
    f2v c01 = __builtin_convertvector(acc01, f2v);
    f2v c23 = __builtin_convertvector(acc23, f2v);
    float f0 = c01.x, f1 = c01.y, fA = c23.x, fB = c23.y;
    f0 += __shfl_xor(f0, 32);
    f1 += __shfl_xor(f1, 32);
    fA += __shfl_xor(fA, 32);
    fB += __shfl_xor(fB, 32);

    if (half == 0) {
        float inv = 1.f / den;
        float4 bi = *(const float4*)(bias + c0);
        float o0 = f0 * inv + bi.x;
        float o1 = f1 * inv + bi.y;
        float o2 = fA * inv + bi.z;
        float o3 = fB * inv + bi.w;
        if (mode == 1) {
            float4 r = *(const float4*)(RES + (size_t)d * 128 + c0);
            float4 rb = *(const float4*)(resB + c0);
            o0 += r.x + rb.x; o1 += r.y + rb.y;
            o2 += r.z + rb.z; o3 += r.w + rb.w;
        } else {
            uint2 hv = *(const uint2*)(hbf + (size_t)d * 128 + c0);
            f2v g01 = __builtin_convertvector(bit_h2(hv.x), f2v);
            f2v g23 = __builtin_convertvector(bit_h2(hv.y), f2v);
            o0 += g01.x; o1 += g01.y; o2 += g23.x; o3 += g23.y;
        }
        float4 gm = *(const float4*)(mm + c0);
        float4 gv = *(const float4*)(vv + c0);
        float4 gg = *(const float4*)(g + c0);
        float4 gb = *(const float4*)(bb + c0);
        o0 = fmaxf((o0 - gm.x) * rsqrtf(gv.x + BN_EPS) * gg.x + gb.x, 0.f);
        o1 = fmaxf((o1 - gm.y) * rsqrtf(gv.y + BN_EPS) * gg.y + gb.y, 0.f);
        o2 = fmaxf((o2 - gm.z) * rsqrtf(gv.z + BN_EPS) * gg.z + gb.z, 0.f);
        o3 = fmaxf((o3 - gm.w) * rsqrtf(gv.w + BN_EPS) * gg.w + gb.w, 0.f);
        h2 s01 = {(_Float16)o0, (_Float16)o1};
        h2 s23 = {(_Float16)o2, (_Float16)o3};
        uint2 w;
        w.x = bit_u(s01);
        w.y = bit_u(s23);
        *(uint2*)(hbf + (size_t)d * 128 + c0) = w;
    }
}

// ---------------------------------------------------------------------------
// Fused GATv2 agg + epilogue, H=1 C=47 (layer 3). 16-lane edge groups
// (residue class grp mod 4), 4 gathers in flight, packed fp16 math, DPP
// 16-lane reduce. Edge offsets PRELOADED + __shfl broadcast. Control flow is
// WAVE-UNIFORM: full 16-edge blocks (no gating) + gated uniform tail, so no
// __shfl ever executes with inactive source lanes (R2 bug). Overflow >64
// uses divergent but shfl-free direct loads. esrc byte offsets (>>1 for
// 256 B rows). XLR rows of 128 fp16: xl @0..47(pad), xr @64..111(pad).
// out = BN(agg + b3 + RES + res2_b), no relu.
// ---------------------------------------------------------------------------
__global__ __launch_bounds__(256) void gat_agg1_fused(
    const int* __restrict__ cnt, const int* __restrict__ esrc,
    const _Float16* __restrict__ xlr, const float* __restrict__ att,
    const float* __restrict__ RES, const float* __restrict__ resB,
    const float* __restrict__ bias,
    const float* __restrict__ g, const float* __restrict__ bb,
    const float* __restrict__ mm, const float* __restrict__ vv,
    float* __restrict__ out, int N) {
    int d = blockIdx.x * 4 + (threadIdx.x >> 6);
    if (d >= N) return;
    int lane = threadIdx.x & 63;
    int gl = lane & 15, grp = lane >> 4;
    const char* xb = (const char*)xlr + gl * 8;

    int beg = d * SLOT;
    int cnt_d = cnt[d];
    int myoff = esrc[beg + lane] >> 1;     // coalesced; junk beyond cnt_d unused

    uint2 xrv = *(const uint2*)(xb + (size_t)d * 256 + 128);
    h2 xr01 = bit_h2(xrv.x), xr23 = bit_h2(xrv.y);
    float atf[4];
#pragma unroll
    for (int k = 0; k < 4; k++) {
        int c = gl * 4 + k;
        atf[k] = (c < 47) ? att[c] : 0.f;
    }
    h2 at01 = {(_Float16)atf[0], (_Float16)atf[1]};
    h2 at23 = {(_Float16)atf[2], (_Float16)atf[3]};

    int nmain = cnt_d < 64 ? cnt_d : 64;
    float den = 0.f;
    h2 acc01 = {(_Float16)0.f, (_Float16)0.f};
    h2 acc23 = acc01;
    // full 16-edge blocks (uniform trip count; all shfl indices valid)
    int nb = nmain >> 4;
    for (int t = 0; t < nb; t++) {
        int e = t * 16 + grp;
        int o0 = __shfl(myoff, e);
        int o1 = __shfl(myoff, e + 4);
        int o2 = __shfl(myoff, e + 8);
        int o3 = __shfl(myoff, e + 12);
        uint2 u0 = *(const uint2*)(xb + o0);
        uint2 u1 = *(const uint2*)(xb + o1);
        uint2 u2 = *(const uint2*)(xb + o2);
        uint2 u3 = *(const uint2*)(xb + o3);
        edge16(u0, xr01, xr23, at01, at23, den, acc01, acc23, 1.f);
        edge16(u1, xr01, xr23, at01, at23, den, acc01, acc23, 1.f);
        edge16(u2, xr01, xr23, at01, at23, den, acc01, acc23, 1.f);
        edge16(u3, xr01, xr23, at01, at23, den, acc01, acc23, 1.f);
    }
    // gated tail: uniform trip count; act is uniform within each 16-lane
    // group so the DPP reduce stays group-local-clean
    int base = nb * 16;
    int rem = nmain - base;                 // 0..15
    int tail_it = (rem + 3) >> 2;
    for (int i = 0; i < tail_it; i++) {
        int idx = base + grp + 4 * i;
        bool act = idx < nmain;
        int o = __shfl(myoff, act ? idx : 0);
        uint2 u0 = *(const uint2*)(xb + o);
        edge16(u0, xr01, xr23, at01, at23, den, acc01, acc23, act ? 1.f : 0.f);
    }
    // rare cnt>64 overflow: direct loads (divergent but shfl-free)
    for (int j = beg + 64 + grp; j < beg + cnt_d; j += 4) {
        int o = esrc[j] >> 1;
        uint2 u0 = *(const uint2*)(xb + o);
        edge16(u0, xr01, xr23, at01, at23, den, acc01, acc23, 1.f);
    }
    den += __shfl_xor(den, 16);
    den += __shfl_xor(den, 32);
    f2v c01 = __builtin_convertvector(acc01, f2v);
    f2v c23 = __builtin_convertvector(acc23, f2v);
    float f[4] = {c01.x, c01.y, c23.x, c23.y};
#pragma unroll
    for (int k = 0; k < 4; k++) {
        f[k] += __shfl_xor(f[k], 16);
        f[k] += __shfl_xor(f[k], 32);
    }
    if (grp == 0 && gl < 12) {
        float inv = 1.f / den;
#pragma unroll
        for (int k = 0; k < 4; k++) {
            int c = gl * 4 + k;
            if (c < 47) {
                float o = f[k] * inv + bias[c] + RES[(size_t)d * 48 + c] + resB[c];
                o = (o - mm[c]) * rsqrtf(vv[c] + BN_EPS) * g[c] + bb[c];
                out[(size_t)d * 47 + c] = o;
            }
        }
    }
}

// ---------------------------------------------------------------------------
extern "C" void kernel_launch(void* const* d_in, const int* in_sizes, int n_in,
                              void* d_out, int out_size, void* d_ws, size_t ws_size,
                              hipStream_t stream) {
    const float* x      = (const float*)d_in[0];
    const int*   ei     = (const int*)d_in[1];
    const float* w1_src = (const float*)d_in[2];
    const float* w1_dst = (const float*)d_in[3];
    const float* att1   = (const float*)d_in[4];
    const float* b1     = (const float*)d_in[5];
    const float* bn1_g  = (const float*)d_in[6];
    const float* bn1_b  = (const float*)d_in[7];
    const float* bn1_m  = (const float*)d_in[8];
    const float* bn1_v  = (const float*)d_in[9];
    const float* res0_w = (const float*)d_in[10];
    const float* res0_b = (const float*)d_in[11];
    const float* w2_src = (const float*)d_in[12];
    const float* w2_dst = (const float*)d_in[13];
    const float* att2   = (const float*)d_in[14];
    const float* b2     = (const float*)d_in[15];
    const float* bn2_g  = (const float*)d_in[16];
    const float* bn2_b  = (const float*)d_in[17];
    const float* bn2_m  = (const float*)d_in[18];
    const float* bn2_v  = (const float*)d_in[19];
    const float* w3_src = (const float*)d_in[20];
    const float* w3_dst = (const float*)d_in[21];
    const float* att3   = (const float*)d_in[22];
    const float* b3     = (const float*)d_in[23];
    const float* bn3_g  = (const float*)d_in[24];
    const float* bn3_b  = (const float*)d_in[25];
    const float* bn3_m  = (const float*)d_in[26];
    const float* bn3_v  = (const float*)d_in[27];
    const float* res2_w = (const float*)d_in[28];
    const float* res2_b = (const float*)d_in[29];

    const int F_IN = 100;
    const int KP = 128;
    const int NC1 = 384, NC2 = 256, NC3 = 144;
    int N = in_sizes[0] / F_IN;
    int E = in_sizes[1] / 2;
    int Etot = E + N;
    const int* src = ei;
    const int* dst = ei + E;
    int nbuck = (N + 255) >> 8;   // dst buckets of 256 nodes

    // ---- workspace layout (float units) ----
    float* ws = (float*)d_ws;
    size_t o = 0;
    _Float16* XLR = (_Float16*)(ws + o); o += (size_t)N * 128;   // [N,256] fp16
    float* B_res = ws + o; o += (size_t)N * 128;                 // residual fp32
    _Float16* A_h = (_Float16*)(ws + o); o += (size_t)N * 64;    // [N,128] fp16
    _Float16* Wb1 = (_Float16*)(ws + o); o += (size_t)KP * NC1 / 2;
    _Float16* Wb2 = (_Float16*)(ws + o); o += (size_t)KP * NC2 / 2;
    _Float16* Wb3 = (_Float16*)(ws + o); o += (size_t)KP * NC3 / 2;
    int* I_cnt  = (int*)(ws + o); o += N;
    int* I_esrc = (int*)(ws + o); o += (size_t)N * SLOT + 4;
    int* I_gcnt = (int*)(ws + o); o += 256;                      // bucket counts
    int* I_bbuf = (int*)(ws + o); o += (size_t)nbuck * BCAP;     // binned edges
    (void)ws_size; (void)n_in; (void)out_size;

    int mtiles = (N + 15) / 16;
    int aggGrid = (N + 3) / 4;
    int gemmGrid = (mtiles + 3) / 4;   // 1 wave per row-tile

    // 1. zero bucket counters (tiny)
    hipMemsetAsync(I_gcnt, 0, 256 * sizeof(int), stream);

    // 2. phase A binning + prep (vectorized conv + weight pack)
    {
        int nbA = 512;
        int convTot = N * 32;
        int packTot = KP * (NC1 + NC2 + NC3);
        int pb = (convTot + packTot + 255) / 256;
        prep_bin_k<<<nbA + pb, 256, 0, stream>>>(
            src, dst, E, Etot, I_gcnt, I_bbuf, nbA, x, A_h, N,
            w1_src, w1_dst, res0_w, w2_src, w2_dst, w3_src, w3_dst, res2_w,
            Wb1, Wb2, Wb3);
    }

    // 3. layer-1 GEMM (A-resident) + phase B CSR build (grid-stuffed first;
    //    its LDS-atomic latency hides under the MFMA work)
    mfma_gemm<4><<<nbuck + gemmGrid, 256, 0, stream>>>(
        A_h, Wb1, XLR, B_res, N, NC1, 384, 256, 384, 0, 256, 128,
        I_gcnt, I_bbuf, I_esrc, I_cnt, nbuck, N);
    // 4. layer-1 agg + epilogue
    gat_agg4_fused<<<aggGrid, 256, 0, stream>>>(
        I_cnt, I_esrc, XLR, att1, B_res, res0_b, b1,
        bn1_g, bn1_b, bn1_m, bn1_v, A_h, N, 1);

    // 5. layer-2 GEMM
    mfma_gemm<4><<<gemmGrid, 256, 0, stream>>>(
        A_h, Wb2, XLR, B_res, N, NC2, 256, 256, 256, 0, 256, 128,
        nullptr, nullptr, nullptr, nullptr, 0, N);
    // 6. layer-2 agg + epilogue
    gat_agg4_fused<<<aggGrid, 256, 0, stream>>>(
        I_cnt, I_esrc, XLR, att2, nullptr, nullptr, b2,
        bn2_g, bn2_b, bn2_m, bn2_v, A_h, N, 2);

    // 7. layer-3 GEMM
    mfma_gemm<3><<<gemmGrid, 256, 0, stream>>>(
        A_h, Wb3, XLR, B_res, N, NC3, 141, 94, 47, 17, 128, 48,
        nullptr, nullptr, nullptr, nullptr, 0, N);
    // 8. layer-3 agg + epilogue
    gat_agg1_fused<<<aggGrid, 256, 0, stream>>>(
        I_cnt, I_esrc, XLR, att3, B_res, res2_b, b3,
        bn3_g, bn3_b, bn3_m, bn3_v, (float*)d_out, N);
}

// Round 5
// 323.816 us; speedup vs baseline: 1.2229x; 1.0164x over previous
//
#include <hip/hip_runtime.h>
#include <math.h>

#define BN_EPS 1e-5f
#define SLOT 96              // padded CSR slots per node (avg deg ~17, P(>96)~0)
#define LN16 2.7725887f      // exp bias so packed-fp16 accumulators can't overflow
#define BCAP 5120            // per-bucket capacity (mean 4352, +11 sigma)

typedef _Float16 h2 __attribute__((ext_vector_type(2)));
typedef _Float16 h4 __attribute__((ext_vector_type(4)));
typedef _Float16 h8 __attribute__((ext_vector_type(8)));
typedef float f2v __attribute__((ext_vector_type(2)));
typedef float float4v __attribute__((ext_vector_type(4)));

static __device__ inline h2 bit_h2(unsigned u) {
    union { unsigned u; h2 h; } c; c.u = u; return c.h;
}
static __device__ inline unsigned bit_u(h2 h) {
    union { unsigned u; h2 h; } c; c.h = h; return c.u;
}

// DPP partial-sum adds (VALU pipe). 0xB1=quad xor1, 0x4E=quad xor2,
// 0x141=row_half_mirror (8-lane), 0x140=row_mirror (16-lane).
template <int CTRL>
static __device__ inline float dpp_add(float x) {
    int y = __builtin_amdgcn_update_dpp(0, __float_as_int(x), CTRL, 0xF, 0xF, true);
    return x + __int_as_float(y);
}
static __device__ inline float red8_dpp(float t) {
    t = dpp_add<0xB1>(t); t = dpp_add<0x4E>(t); t = dpp_add<0x141>(t);
    return t;
}
static __device__ inline float red16_dpp(float t) {
    t = dpp_add<0xB1>(t); t = dpp_add<0x4E>(t); t = dpp_add<0x141>(t);
    t = dpp_add<0x140>(t);
    return t;
}

// ---------------------------------------------------------------------------
// Weight packing: [p0|p1|p2] -> MFMA B-fragment-major fp16.
// ---------------------------------------------------------------------------
static __device__ inline void pack_one(int idx,
                                       const float* p0, const float* p1,
                                       const float* p2,
                                       int w0, int w1, int w2,
                                       int Ksrc, int Ncat,
                                       _Float16* out) {
    int k = idx / Ncat, n = idx - k * Ncat;
    float v = 0.f;
    if (k < Ksrc) {
        if (n < w0) v = p0[(size_t)k * w0 + n];
        else if (n < w0 + w1) v = p1[(size_t)k * w1 + (n - w0)];
        else if (w2 > 0 && n < w0 + w1 + w2) v = p2[(size_t)k * w2 + (n - w0 - w1)];
    }
    int kt = k >> 5, kr = k & 31;
    int quad = kr >> 3, j = kr & 7;
    int nt = n >> 4, nr = n & 15;
    int ntiles = Ncat >> 4;
    out[((size_t)(kt * ntiles + nt) * 64 + quad * 16 + nr) * 8 + j] = (_Float16)v;
}

// ---------------------------------------------------------------------------
// prep + bin (phase A), grid-stuffed.
// Bin: two-sweep per block. Sweep 1: LDS histogram over buckets (dst>>8).
// Reserve: one global atomicAdd per (block,bucket). Sweep 2: LDS-atomic
// rank, write packed (dlow<<16|src) into contiguous per-bucket runs.
// Prep: x fp32 -> A fp16 [N,128] zero-padded, vectorized; pack 3 weights.
// ---------------------------------------------------------------------------
__global__ __launch_bounds__(256) void prep_bin_k(
    const int* __restrict__ src, const int* __restrict__ dst, int E, int Etot,
    int* __restrict__ gcnt, int* __restrict__ bbuf, int nbA,
    const float* __restrict__ x, _Float16* __restrict__ A, int N,
    const float* __restrict__ w1s, const float* __restrict__ w1d,
    const float* __restrict__ r0w, const float* __restrict__ w2s,
    const float* __restrict__ w2d, const float* __restrict__ w3s,
    const float* __restrict__ w3d, const float* __restrict__ r2w,
    _Float16* __restrict__ Wb1, _Float16* __restrict__ Wb2,
    _Float16* __restrict__ Wb3) {
    if ((int)blockIdx.x < nbA) {
        __shared__ int hist[256];
        __shared__ int base[256];
        int tid = threadIdx.x;
        hist[tid] = 0;
        __syncthreads();
        int per = (Etot + nbA - 1) / nbA;
        int e0 = blockIdx.x * per;
        int e1 = min(e0 + per, Etot);
        for (int i = e0 + tid; i < e1; i += 256) {
            int d = (i < E) ? dst[i] : (i - E);
            atomicAdd(&hist[d >> 8], 1);
        }
        __syncthreads();
        int h = hist[tid];
        if (h) base[tid] = atomicAdd(&gcnt[tid], h);
        __syncthreads();
        for (int i = e0 + tid; i < e1; i += 256) {
            int d = (i < E) ? dst[i] : (i - E);
            int s = (i < E) ? src[i] : (i - E);
            int b = d >> 8;
            int off = atomicAdd(&base[b], 1);
            if (off < BCAP) bbuf[(size_t)b * BCAP + off] = ((d & 255) << 16) | s;
        }
        return;
    }
    const int S1 = 128 * 384, S2 = 128 * 256, S3 = 128 * 144;
    int convTot = N * 32;
    int idx = (blockIdx.x - nbA) * 256 + threadIdx.x;
    if (idx < convTot) {
        int n = idx >> 5, t = idx & 31;
        float4 v = {0.f, 0.f, 0.f, 0.f};
        if (t < 25) v = *(const float4*)(x + (size_t)n * 100 + t * 4);
        h4 o = {(_Float16)v.x, (_Float16)v.y, (_Float16)v.z, (_Float16)v.w};
        *(h4*)(A + (size_t)n * 128 + t * 4) = o;
        return;
    }
    int p = idx - convTot;
    if (p < S1) pack_one(p, w1s, w1d, r0w, 128, 128, 128, 100, 384, Wb1);
    else if (p < S1 + S2) pack_one(p - S1, w2s, w2d, nullptr, 128, 128, 0, 128, 256, Wb2);
    else if (p < S1 + S2 + S3) pack_one(p - S1 - S2, w3s, w3d, r2w, 47, 47, 47, 128, 144, Wb3);
}

// ---------------------------------------------------------------------------
// MFMA fp16 GEMM, A-resident: one wave = one 16-row tile x ALL columns.
// Layer-1 launch additionally carries the bin phase B (scatN buckets, one
// block per bucket, dispatched FIRST so their latency hides under MFMA):
// build padded-CSR via LDS atomics + cached stores into a 98KB per-block
// window; also emits cnt[].
// ---------------------------------------------------------------------------
template <int NT>
__global__ __launch_bounds__(256) void mfma_gemm(const _Float16* __restrict__ A,
                                                 const _Float16* __restrict__ Bp,
                                                 _Float16* __restrict__ XLR,
                                                 float* __restrict__ RES,
                                                 int M, int Ncat,
                                                 int ncat_valid, int res_off,
                                                 int bf_remap, int bf_shift,
                                                 int bf_stride, int res_stride,
                                                 const int* __restrict__ gcnt,
                                                 const int* __restrict__ bbuf,
                                                 int* __restrict__ esrc,
                                                 int* __restrict__ cnt,
                                                 int scatN, int Nn) {
    __shared__ int lcnt[256];
    int bid = blockIdx.x;
    if (bid < scatN) {
        int tid = threadIdx.x;
        lcnt[tid] = 0;
        __syncthreads();
        int cb = gcnt[bid];
        if (cb > BCAP) cb = BCAP;
        const int* bp = bbuf + (size_t)bid * BCAP;
        int b0 = bid << 8;
        for (int i = tid; i < cb; i += 256) {
            int w = bp[i];
            int dl = (w >> 16) & 255;
            int s = w & 0xFFFF;
            int pos = atomicAdd(&lcnt[dl], 1);
            esrc[(size_t)(b0 + dl) * SLOT + pos] = s << 9;
        }
        __syncthreads();
        int d = b0 + tid;
        if (d < Nn) cnt[d] = lcnt[tid];
        return;
    }
    int mt = ((bid - scatN) * 256 + threadIdx.x) >> 6;
    int lane = threadIdx.x & 63;
    int mtiles = M >> 4;
    if (mt >= mtiles) return;
    int ngroups = Ncat / (16 * NT);
    int ntiles = Ncat >> 4;
    int quad = lane >> 4;
    int nr = lane & 15;
    int row = mt * 16 + nr;

    // whole-K A strip in registers (loaded once)
    h8 a[4];
#pragma unroll
    for (int kt = 0; kt < 4; kt++)
        a[kt] = *(const h8*)(A + (size_t)row * 128 + kt * 32 + quad * 8);

    int rowb = mt * 16 + quad * 4;
    for (int ng = 0; ng < ngroups; ng++) {
        float4v acc[NT];
#pragma unroll
        for (int t = 0; t < NT; t++) acc[t] = (float4v){0.f, 0.f, 0.f, 0.f};
#pragma unroll
        for (int kt = 0; kt < 4; kt++) {
            const _Float16* bbase =
                Bp + ((size_t)(kt * ntiles + ng * NT) * 64 + lane) * 8;
#pragma unroll
            for (int t = 0; t < NT; t++) {
                h8 b = *(const h8*)(bbase + (size_t)t * 512);
                acc[t] = __builtin_amdgcn_mfma_f32_16x16x32_f16(a[kt], b, acc[t], 0, 0, 0);
            }
        }
#pragma unroll
        for (int t = 0; t < NT; t++) {
            int col = (ng * NT + t) * 16 + nr;
            if (col >= ncat_valid) continue;
            if (col < res_off) {
                int bc = (col >= bf_remap) ? col + bf_shift : col;
#pragma unroll
                for (int r = 0; r < 4; r++)
                    XLR[(size_t)(rowb + r) * bf_stride + bc] = (_Float16)acc[t][r];
            } else {
                int rc = col - res_off;
#pragma unroll
                for (int r = 0; r < 4; r++)
                    RES[(size_t)(rowb + r) * res_stride + rc] = acc[t][r];
            }
        }
    }
}

// ---------------------------------------------------------------------------
// Per-edge GATv2 micro-ops (packed fp16).
// ---------------------------------------------------------------------------
static __device__ inline void edge8(uint2 u, h2 xr01, h2 xr23, h2 at01,
                                    h2 at23, float& den, h2& acc01, h2& acc23,
                                    float gate) {
    const h2 NS = {(_Float16)0.2f, (_Float16)0.2f};
    h2 a01 = bit_h2(u.x), a23 = bit_h2(u.y);
    h2 v01 = a01 + xr01, v23 = a23 + xr23;
    v01 = __builtin_elementwise_max(v01, v01 * NS);
    v23 = __builtin_elementwise_max(v23, v23 * NS);
    h2 t2 = v01 * at01 + v23 * at23;
    f2v tf = __builtin_convertvector(t2, f2v);
    float t = red8_dpp(tf.x + tf.y);
    float p = __expf(t - LN16) * gate;
    den += p;
    h2 P = {(_Float16)p, (_Float16)p};
    acc01 = P * a01 + acc01;
    acc23 = P * a23 + acc23;
}
static __device__ inline void edge16(uint2 u, h2 xr01, h2 xr23, h2 at01,
                                     h2 at23, float& den, h2& acc01,
                                     h2& acc23, float gate) {
    const h2 NS = {(_Float16)0.2f, (_Float16)0.2f};
    h2 a01 = bit_h2(u.x), a23 = bit_h2(u.y);
    h2 v01 = a01 + xr01, v23 = a23 + xr23;
    v01 = __builtin_elementwise_max(v01, v01 * NS);
    v23 = __builtin_elementwise_max(v23, v23 * NS);
    h2 t2 = v01 * at01 + v23 * at23;
    f2v tf = __builtin_convertvector(t2, f2v);
    float t = red16_dpp(tf.x + tf.y);
    float p = __expf(t - LN16) * gate;
    den += p;
    h2 P = {(_Float16)p, (_Float16)p};
    acc01 = P * a01 + acc01;
    acc23 = P * a23 + acc23;
}

// ---------------------------------------------------------------------------
// Fused GATv2 agg + epilogue, H=4 C=32. One wave per dst node; half-wave edge
// pairs; lane owns 4 channels as 2 packed fp16 pairs. SINGLE-TRIP GATHER:
// lane k-th slot covers edge 2k+half, k<12 -> deg<=24 (96% of nodes) issues
// ALL gathers before any compute (12 in flight). Epilogue inputs (RES row /
// hbf_prev, bias) hoisted to overlap gather latency. All control flow
// wave-uniform; inactive edges contribute 0 via gate. esrc = byte offsets.
// XLR rows 512 B: xl @0, xr @256.
// mode 1: h = relu(BN(agg + bias + RES + resB))     -> hbf fp16
// mode 2: h = relu(BN(agg + bias + fp16(hbf_prev))) -> hbf in-place
// ---------------------------------------------------------------------------
__global__ __launch_bounds__(256) void gat_agg4_fused(
    const int* __restrict__ cnt, const int* __restrict__ esrc,
    const _Float16* __restrict__ xlr, const float* __restrict__ att,
    const float* __restrict__ RES, const float* __restrict__ resB,
    const float* __restrict__ bias,
    const float* __restrict__ g, const float* __restrict__ bb,
    const float* __restrict__ mm, const float* __restrict__ vv,
    _Float16* __restrict__ hbf, int N, int mode) {
    int d = blockIdx.x * 4 + (threadIdx.x >> 6);
    if (d >= N) return;
    int lane = threadIdx.x & 63;
    int half = lane >> 5;
    int gl = lane & 31;
    int c0 = gl * 4;
    const char* xb = (const char*)xlr + c0 * 2;

    int beg = d * SLOT;
    int cnt_d = cnt[d];
    int myoff = esrc[beg + lane];          // coalesced; junk beyond cnt_d unused

    uint2 xrv = *(const uint2*)(xb + (size_t)d * 512 + 256);
    float4 af = *(const float4*)(att + c0);
    // hoisted epilogue inputs -- overlap their latency with the gathers
    float4 rres = {0.f, 0.f, 0.f, 0.f};
    uint2 hprev = {0u, 0u};
    if (mode == 1) rres = *(const float4*)(RES + (size_t)d * 128 + c0);
    else hprev = *(const uint2*)(hbf + (size_t)d * 128 + c0);
    float4 bi = *(const float4*)(bias + c0);

    h2 xr01 = bit_h2(xrv.x), xr23 = bit_h2(xrv.y);
    h2 at01 = {(_Float16)af.x, (_Float16)af.y};
    h2 at23 = {(_Float16)af.z, (_Float16)af.w};

    // batched gather: ALL loads issued before compute (deg<=24 single trip)
    int K = (cnt_d + 1) >> 1;              // per-lane edge count (edges 2k+half)
    int KB = K < 12 ? K : 12;              // in-register batch (uniform)
    uint2 u[12];
#pragma unroll
    for (int k = 0; k < 12; k++) {
        if (k < KB) {
            int ee = 2 * k + half;
            int ec = ee < cnt_d ? ee : 0;
            int o = __shfl(myoff, ec);
            u[k] = *(const uint2*)(xb + o);
        }
    }
    float den = 0.f;
    h2 acc01 = {(_Float16)0.f, (_Float16)0.f};
    h2 acc23 = acc01;
#pragma unroll
    for (int k = 0; k < 12; k++) {
        if (k < KB) {
            int ee = 2 * k + half;
            edge8(u[k], xr01, xr23, at01, at23, den, acc01, acc23,
                  ee < cnt_d ? 1.f : 0.f);
        }
    }
    // overflow deg>24 (rare): 2 at a time, predicated; covers cnt>64 too
    for (int e = 24; e < cnt_d; e += 2) {
        int ee = e + half;
        bool act = ee < cnt_d;
        int ec = act ? ee : cnt_d - 1;
        int o = __shfl(myoff, ec < 64 ? ec : 0);
        if (ec >= 64) o = esrc[beg + ec];
        uint2 u0 = *(const uint2*)(xb + o);
        edge8(u0, xr01, xr23, at01, at23, den, acc01, acc23, act ? 1.f : 0.f);
    }
    den += __shfl_xor(den, 32);
    f2v c01 = __builtin_convertvector(acc01, f2v);
    f2v c23 = __builtin_convertvector(acc23, f2v);
    float f0 = c01.x, f1 = c01.y, fA = c23.x, fB = c23.y;
    f0 += __shfl_xor(f0, 32);
    f1 += __shfl_xor(f1, 32);
    fA += __shfl_xor(fA, 32);
    fB += __shfl_xor(fB, 32);

    if (half == 0) {
        float inv = 1.f / den;
        float o0 = f0 * inv + bi.x;
        float o1 = f1 * inv + bi.y;
        float o2 = fA * inv + bi.z;
        float o3 = fB * inv + bi.w;
        if (mode == 1) {
            float4 rb = *(const float4*)(resB + c0);
            o0 += rres.x + rb.x; o1 += rres.y + rb.y;
            o2 += rres.z + rb.z; o3 += rres.w + rb.w;
        } else {
            f2v g01 = __builtin_convertvector(bit_h2(hprev.x), f2v);
            f2v g23 = __builtin_convertvector(bit_h2(hprev.y), f2v);
            o0 += g01.x; o1 += g01.y; o2 += g23.x; o3 += g23.y;
        }
        float4 gm = *(const float4*)(mm + c0);
        float4 gv = *(const float4*)(vv + c0);
        float4 gg = *(const float4*)(g + c0);
        float4 gb = *(const float4*)(bb + c0);
        o0 = fmaxf((o0 - gm.x) * rsqrtf(gv.x + BN_EPS) * gg.x + gb.x, 0.f);
        o1 = fmaxf((o1 - gm.y) * rsqrtf(gv.y + BN_EPS) * gg.y + gb.y, 0.f);
        o2 = fmaxf((o2 - gm.z) * rsqrtf(gv.z + BN_EPS) * gg.z + gb.z, 0.f);
        o3 = fmaxf((o3 - gm.w) * rsqrtf(gv.w + BN_EPS) * gg.w + gb.w, 0.f);
        h2 s01 = {(_Float16)o0, (_Float16)o1};
        h2 s23 = {(_Float16)o2, (_Float16)o3};
        uint2 w;
        w.x = bit_u(s01);
        w.y = bit_u(s23);
        *(uint2*)(hbf + (size_t)d * 128 + c0) = w;
    }
}

// ---------------------------------------------------------------------------
// Fused GATv2 agg + epilogue, H=1 C=47 (layer 3). 16-lane edge groups
// (residue class grp mod 4), packed fp16 math, DPP 16-lane reduce.
// SINGLE-TRIP GATHER: lane's k-th slot covers edge grp+4k, k<12 -> deg<=48
// (~100% of nodes) issues ALL gathers before compute (12 in flight). RES row
// hoisted. All control flow wave-uniform; every __shfl runs with 64 active
// lanes, indices < 64. esrc byte offsets (>>1 for 256 B rows). XLR rows of
// 128 fp16: xl @0..47(pad), xr @64..111(pad).
// out = BN(agg + b3 + RES + res2_b), no relu.
// ---------------------------------------------------------------------------
__global__ __launch_bounds__(256) void gat_agg1_fused(
    const int* __restrict__ cnt, const int* __restrict__ esrc,
    const _Float16* __restrict__ xlr, const float* __restrict__ att,
    const float* __restrict__ RES, const float* __restrict__ resB,
    const float* __restrict__ bias,
    const float* __restrict__ g, const float* __restrict__ bb,
    const float* __restrict__ mm, const float* __restrict__ vv,
    float* __restrict__ out, int N) {
    int d = blockIdx.x * 4 + (threadIdx.x >> 6);
    if (d >= N) return;
    int lane = threadIdx.x & 63;
    int gl = lane & 15, grp = lane >> 4;
    const char* xb = (const char*)xlr + gl * 8;

    int beg = d * SLOT;
    int cnt_d = cnt[d];
    int myoff = esrc[beg + lane] >> 1;     // coalesced; junk beyond cnt_d unused

    uint2 xrv = *(const uint2*)(xb + (size_t)d * 256 + 128);
    // hoisted epilogue input: RES row slice (16B aligned: d*192B + gl*16B;
    // gl>=12 reads pad/next row inside the N*128-float B_res buffer -- safe)
    float4 rres = *(const float4*)(RES + (size_t)d * 48 + gl * 4);

    h2 xr01 = bit_h2(xrv.x), xr23 = bit_h2(xrv.y);
    float atf[4];
#pragma unroll
    for (int k = 0; k < 4; k++) {
        int c = gl * 4 + k;
        atf[k] = (c < 47) ? att[c] : 0.f;
    }
    h2 at01 = {(_Float16)atf[0], (_Float16)atf[1]};
    h2 at23 = {(_Float16)atf[2], (_Float16)atf[3]};

    int nmain = cnt_d < 64 ? cnt_d : 64;
    // batched gather: lane's k-th slot = edge grp+4k; deg<=48 single trip
    int nb1 = nmain < 48 ? nmain : 48;
    int K1 = (nb1 + 3) >> 2;               // uniform
    uint2 u[12];
#pragma unroll
    for (int k = 0; k < 12; k++) {
        if (k < K1) {
            int idx = grp + 4 * k;
            int ec = idx < nmain ? idx : 0;
            int o = __shfl(myoff, ec);
            u[k] = *(const uint2*)(xb + o);
        }
    }
    float den = 0.f;
    h2 acc01 = {(_Float16)0.f, (_Float16)0.f};
    h2 acc23 = acc01;
#pragma unroll
    for (int k = 0; k < 12; k++) {
        if (k < K1) {
            int idx = grp + 4 * k;
            edge16(u[k], xr01, xr23, at01, at23, den, acc01, acc23,
                   idx < nmain ? 1.f : 0.f);
        }
    }
    // deg>48 residue (uniform loop; gated)
    for (int ibase = 48; ibase < nmain; ibase += 4) {
        int idx = ibase + grp;
        bool act = idx < nmain;
        int o = __shfl(myoff, act ? idx : 0);
        uint2 u0 = *(const uint2*)(xb + o);
        edge16(u0, xr01, xr23, at01, at23, den, acc01, acc23, act ? 1.f : 0.f);
    }
    // rare cnt>64 overflow: direct loads (divergent but shfl-free)
    for (int j = beg + 64 + grp; j < beg + cnt_d; j += 4) {
        int o = esrc[j] >> 1;
        uint2 u0 = *(const uint2*)(xb + o);
        edge16(u0, xr01, xr23, at01, at23, den, acc01, acc23, 1.f);
    }
    den += __shfl_xor(den, 16);
    den += __shfl_xor(den, 32);
    f2v c01 = __builtin_convertvector(acc01, f2v);
    f2v c23 = __builtin_convertvector(acc23, f2v);
    float f[4] = {c01.x, c01.y, c23.x, c23.y};
#pragma unroll
    for (int k = 0; k < 4; k++) {
        f[k] += __shfl_xor(f[k], 16);
        f[k] += __shfl_xor(f[k], 32);
    }
    if (grp == 0 && gl < 12) {
        float inv = 1.f / den;
        float rr[4] = {rres.x, rres.y, rres.z, rres.w};
#pragma unroll
        for (int k = 0; k < 4; k++) {
            int c = gl * 4 + k;
            if (c < 47) {
                float o = f[k] * inv + bias[c] + rr[k] + resB[c];
                o = (o - mm[c]) * rsqrtf(vv[c] + BN_EPS) * g[c] + bb[c];
                out[(size_t)d * 47 + c] = o;
            }
        }
    }
}

// ---------------------------------------------------------------------------
extern "C" void kernel_launch(void* const* d_in, const int* in_sizes, int n_in,
                              void* d_out, int out_size, void* d_ws, size_t ws_size,
                              hipStream_t stream) {
    const float* x      = (const float*)d_in[0];
    const int*   ei     = (const int*)d_in[1];
    const float* w1_src = (const float*)d_in[2];
    const float* w1_dst = (const float*)d_in[3];
    const float* att1   = (const float*)d_in[4];
    const float* b1     = (const float*)d_in[5];
    const float* bn1_g  = (const float*)d_in[6];
    const float* bn1_b  = (const float*)d_in[7];
    const float* bn1_m  = (const float*)d_in[8];
    const float* bn1_v  = (const float*)d_in[9];
    const float* res0_w = (const float*)d_in[10];
    const float* res0_b = (const float*)d_in[11];
    const float* w2_src = (const float*)d_in[12];
    const float* w2_dst = (const float*)d_in[13];
    const float* att2   = (const float*)d_in[14];
    const float* b2     = (const float*)d_in[15];
    const float* bn2_g  = (const float*)d_in[16];
    const float* bn2_b  = (const float*)d_in[17];
    const float* bn2_m  = (const float*)d_in[18];
    const float* bn2_v  = (const float*)d_in[19];
    const float* w3_src = (const float*)d_in[20];
    const float* w3_dst = (const float*)d_in[21];
    const float* att3   = (const float*)d_in[22];
    const float* b3     = (const float*)d_in[23];
    const float* bn3_g  = (const float*)d_in[24];
    const float* bn3_b  = (const float*)d_in[25];
    const float* bn3_m  = (const float*)d_in[26];
    const float* bn3_v  = (const float*)d_in[27];
    const float* res2_w = (const float*)d_in[28];
    const float* res2_b = (const float*)d_in[29];

    const int F_IN = 100;
    const int KP = 128;
    const int NC1 = 384, NC2 = 256, NC3 = 144;
    int N = in_sizes[0] / F_IN;
    int E = in_sizes[1] / 2;
    int Etot = E + N;
    const int* src = ei;
    const int* dst = ei + E;
    int nbuck = (N + 255) >> 8;   // dst buckets of 256 nodes

    // ---- workspace layout (float units) ----
    float* ws = (float*)d_ws;
    size_t o = 0;
    _Float16* XLR = (_Float16*)(ws + o); o += (size_t)N * 128;   // [N,256] fp16
    float* B_res = ws + o; o += (size_t)N * 128;                 // residual fp32
    _Float16* A_h = (_Float16*)(ws + o); o += (size_t)N * 64;    // [N,128] fp16
    _Float16* Wb1 = (_Float16*)(ws + o); o += (size_t)KP * NC1 / 2;
    _Float16* Wb2 = (_Float16*)(ws + o); o += (size_t)KP * NC2 / 2;
    _Float16* Wb3 = (_Float16*)(ws + o); o += (size_t)KP * NC3 / 2;
    int* I_cnt  = (int*)(ws + o); o += N;
    int* I_esrc = (int*)(ws + o); o += (size_t)N * SLOT + 4;
    int* I_gcnt = (int*)(ws + o); o += 256;                      // bucket counts
    int* I_bbuf = (int*)(ws + o); o += (size_t)nbuck * BCAP;     // binned edges
    (void)ws_size; (void)n_in; (void)out_size;

    int mtiles = (N + 15) / 16;
    int aggGrid = (N + 3) / 4;
    int gemmGrid = (mtiles + 3) / 4;   // 1 wave per row-tile

    // 1. zero bucket counters (tiny)
    hipMemsetAsync(I_gcnt, 0, 256 * sizeof(int), stream);

    // 2. phase A binning + prep (vectorized conv + weight pack)
    {
        int nbA = 512;
        int convTot = N * 32;
        int packTot = KP * (NC1 + NC2 + NC3);
        int pb = (convTot + packTot + 255) / 256;
        prep_bin_k<<<nbA + pb, 256, 0, stream>>>(
            src, dst, E, Etot, I_gcnt, I_bbuf, nbA, x, A_h, N,
            w1_src, w1_dst, res0_w, w2_src, w2_dst, w3_src, w3_dst, res2_w,
            Wb1, Wb2, Wb3);
    }

    // 3. layer-1 GEMM (A-resident) + phase B CSR build (grid-stuffed first;
    //    its LDS-atomic latency hides under the MFMA work)
    mfma_gemm<4><<<nbuck + gemmGrid, 256, 0, stream>>>(
        A_h, Wb1, XLR, B_res, N, NC1, 384, 256, 384, 0, 256, 128,
        I_gcnt, I_bbuf, I_esrc, I_cnt, nbuck, N);
    // 4. layer-1 agg + epilogue
    gat_agg4_fused<<<aggGrid, 256, 0, stream>>>(
        I_cnt, I_esrc, XLR, att1, B_res, res0_b, b1,
        bn1_g, bn1_b, bn1_m, bn1_v, A_h, N, 1);

    // 5. layer-2 GEMM
    mfma_gemm<4><<<gemmGrid, 256, 0, stream>>>(
        A_h, Wb2, XLR, B_res, N, NC2, 256, 256, 256, 0, 256, 128,
        nullptr, nullptr, nullptr, nullptr, 0, N);
    // 6. layer-2 agg + epilogue
    gat_agg4_fused<<<aggGrid, 256, 0, stream>>>(
        I_cnt, I_esrc, XLR, att2, nullptr, nullptr, b2,
        bn2_g, bn2_b, bn2_m, bn2_v, A_h, N, 2);

    // 7. layer-3 GEMM
    mfma_gemm<3><<<gemmGrid, 256, 0, stream>>>(
        A_h, Wb3, XLR, B_res, N, NC3, 141, 94, 47, 17, 128, 48,
        nullptr, nullptr, nullptr, nullptr, 0, N);
    // 8. layer-3 agg + epilogue
    gat_agg1_fused<<<aggGrid, 256, 0, stream>>>(
        I_cnt, I_esrc, XLR, att3, B_res, res2_b, b3,
        bn3_g, bn3_b, bn3_m, bn3_v, (float*)d_out, N);
}